// Round 11
// baseline (321.489 us; speedup 1.0000x reference)
//
#include <hip/hip_runtime.h>
#include <math.h>

#define K 32
#define G 8
#define SIGMA_V 1.0f
#define RF __builtin_amdgcn_readfirstlane
#define TILE 256           // rows per tile (32 KB stage)
#define TBLK 4             // tiles per block -> 1024 rows/block, grid 1024

// ws layout (floats): raw[G][K][K] @0 (8192), musum[G][K] @8192 (256), cnt[G] @8448
#define RAW_OFF   0
#define MUSUM_OFF 8192
#define CNT_OFF   8448
#define WS_FLOATS 8456

typedef __attribute__((address_space(3))) void lds_void;
typedef __attribute__((address_space(1))) void glb_void;
#define GLL(gsrc, ldst) __builtin_amdgcn_global_load_lds((const glb_void*)(gsrc), (lds_void*)(ldst), 16, 0, 0)

// raw LDS-only barrier: no vmcnt drain (that's __syncthreads' compiler semantic)
#define LGKM_BAR() do { \
  asm volatile("s_waitcnt lgkmcnt(0)" ::: "memory"); \
  __builtin_amdgcn_s_barrier(); \
  __builtin_amdgcn_sched_barrier(0); \
} while (0)

#define OUTER(ac, m, a, b) { \
  ac[0]=fmaf(a.x,b.x,ac[0]);   ac[1]=fmaf(a.x,b.y,ac[1]);   ac[2]=fmaf(a.x,b.z,ac[2]);   ac[3]=fmaf(a.x,b.w,ac[3]); \
  ac[4]=fmaf(a.y,b.x,ac[4]);   ac[5]=fmaf(a.y,b.y,ac[5]);   ac[6]=fmaf(a.y,b.z,ac[6]);   ac[7]=fmaf(a.y,b.w,ac[7]); \
  ac[8]=fmaf(a.z,b.x,ac[8]);   ac[9]=fmaf(a.z,b.y,ac[9]);   ac[10]=fmaf(a.z,b.z,ac[10]); ac[11]=fmaf(a.z,b.w,ac[11]); \
  ac[12]=fmaf(a.w,b.x,ac[12]); ac[13]=fmaf(a.w,b.y,ac[13]); ac[14]=fmaf(a.w,b.z,ac[14]); ac[15]=fmaf(a.w,b.w,ac[15]); \
  m[0]+=b.x; m[1]+=b.y; m[2]+=b.z; m[3]+=b.w; }

// ---- stream + LDS-bucket stats: sequential HBM, permutation resolved in LDS ----
// block = 4 waves; wave w owns groups {2w, 2w+1} across all its tiles.
__global__ __launch_bounds__(256, 4) void gmm_stats4(const float* __restrict__ mu,
                                                     const int* __restrict__ lab,
                                                     float* __restrict__ ws) {
  __shared__ float stg[TILE * K];          // 32 KB sequential-staged rows
  __shared__ int perm[TILE];               // tile-local counting-sorted row ids
  __shared__ int cnt8[G], ofs[G + 1], otmp[G];
  const int tid = threadIdx.x, wave = tid >> 6, lane = tid & 63;
  const int i8 = lane >> 3, j8 = lane & 7;     // compute: 8x8 lane grid, 4x4 tile
  const int lg = lane >> 3, lf = lane & 7;     // staging mapping
  const int tb0 = blockIdx.x * (TILE * TBLK);

  float accA[16], accB[16], msA[4], msB[4];
  #pragma unroll
  for (int e = 0; e < 16; ++e) { accA[e] = 0.f; accB[e] = 0.f; }
  #pragma unroll
  for (int e = 0; e < 4; ++e) { msA[e] = 0.f; msB[e] = 0.f; }
  int cA = 0, cB = 0;
  const int gA = 2 * wave, gB = gA + 1;

  // prologue: stage tile 0 (sequential GLL), then labels (younger -> lv-wait drains GLLs)
  #pragma unroll
  for (int q = 0; q < 8; ++q)
    GLL(mu + (size_t)(tb0 + wave * 64 + q * 8 + lg) * K + lf * 4,
        &stg[(wave * 64 + q * 8) * K]);
  int lv = lab[tb0 + tid];
  if (tid < G) cnt8[tid] = 0;
  LGKM_BAR();

  for (int t = 0; t < TBLK; ++t) {
    const bool more = (t + 1 < TBLK);
    atomicAdd(&cnt8[lv], 1);                   // tile histogram (LDS)
    int lvn = 0;
    if (more) lvn = lab[tb0 + (t + 1) * TILE + tid];   // prefetch next labels
    LGKM_BAR();                                // hist done (no vmem drain)
    if (tid == 0) {
      int o = 0;
      #pragma unroll
      for (int g2 = 0; g2 < G; ++g2) { ofs[g2] = o; otmp[g2] = o; o += cnt8[g2]; }
      ofs[G] = o;
    }
    LGKM_BAR();                                // prefix ready
    { const int p = atomicAdd(&otmp[lv], 1); perm[p] = tid; }
    __syncthreads();                           // perm visible + vmcnt(0): stage(t) landed
    const int sA = RF(ofs[gA]), eA = RF(ofs[gA + 1]);
    const int eB = RF(ofs[gB + 1]);            // sB == eA
    cA += eA - sA; cB += eB - eA;
    for (int i = sA; i < eA; ++i) {            // group 2w rows (LDS random access: free)
      const int r = perm[i];
      const float4 a = *reinterpret_cast<const float4*>(&stg[r * K + i8 * 4]);
      const float4 b = *reinterpret_cast<const float4*>(&stg[r * K + j8 * 4]);
      OUTER(accA, msA, a, b);
    }
    for (int i = eA; i < eB; ++i) {            // group 2w+1 rows
      const int r = perm[i];
      const float4 a = *reinterpret_cast<const float4*>(&stg[r * K + i8 * 4]);
      const float4 b = *reinterpret_cast<const float4*>(&stg[r * K + j8 * 4]);
      OUTER(accB, msB, a, b);
    }
    if (tid < G) cnt8[tid] = 0;                // re-zero for next tile (unused by compute)
    __syncthreads();                           // stage buffer free
    if (more) {                                // issue next tile: latency covered by build
      #pragma unroll
      for (int q = 0; q < 8; ++q)
        GLL(mu + (size_t)(tb0 + (t + 1) * TILE + wave * 64 + q * 8 + lg) * K + lf * 4,
            &stg[(wave * 64 + q * 8) * K]);
      lv = lvn;
    }
  }

  // flush: per-wave groups are distinct -> direct global atomics (1024 blocks x ~2.1K entries)
  float* rawA = ws + RAW_OFF + gA * K * K;
  float* rawB = ws + RAW_OFF + gB * K * K;
  #pragma unroll
  for (int e = 0; e < 16; ++e) {
    const int row = 4 * i8 + (e >> 2), col = 4 * j8 + (e & 3);
    atomicAdd(rawA + row * K + col, accA[e]);
    atomicAdd(rawB + row * K + col, accB[e]);
  }
  if (i8 == 0) {
    #pragma unroll
    for (int e = 0; e < 4; ++e) {
      atomicAdd(ws + MUSUM_OFF + gA * K + j8 * 4 + e, msA[e]);
      atomicAdd(ws + MUSUM_OFF + gB * K + j8 * 4 + e, msB[e]);
    }
  }
  if (lane == 0) {
    atomicAdd(ws + CNT_OFF + gA, (float)cA);
    atomicAdd(ws + CNT_OFF + gB, (float)cB);
  }
}

// ---------------- fallback path (only if B % (TILE*TBLK) != 0): counts + switch-stats ----------------
__global__ __launch_bounds__(256, 8) void gmm_histf(const int* __restrict__ lab,
                                                    float* __restrict__ ws, int B) {
  int c[G];
  #pragma unroll
  for (int g = 0; g < G; ++g) c[g] = 0;
  const int nt = gridDim.x * blockDim.x;
  for (int i = blockIdx.x * blockDim.x + threadIdx.x; i < B; i += nt) {
    const int v = lab[i];
    #pragma unroll
    for (int g = 0; g < G; ++g) c[g] += (v == g) ? 1 : 0;
  }
  const int lane = threadIdx.x & 63;
  #pragma unroll
  for (int g = 0; g < G; ++g) {
    int t = c[g];
    #pragma unroll
    for (int o = 32; o >= 1; o >>= 1) t += __shfl_xor(t, o);
    if (lane == 0) atomicAdd(&ws[CNT_OFF + g], (float)t);
  }
}

#define ACC_CASE(gc_, Av, Bv_) do{ \
  facc[gc_][0]=fmaf(Av.x,Bv_.x,facc[gc_][0]); facc[gc_][1]=fmaf(Av.x,Bv_.y,facc[gc_][1]); \
  facc[gc_][2]=fmaf(Av.y,Bv_.x,facc[gc_][2]); facc[gc_][3]=fmaf(Av.y,Bv_.y,facc[gc_][3]); \
  if (a_blk==0){ msum[gc_][0]+=Bv_.x; msum[gc_][1]+=Bv_.y; } }while(0)
#define PROC(gv, Av, Bv_) switch(gv){ \
  case 0: ACC_CASE(0,Av,Bv_); break; case 1: ACC_CASE(1,Av,Bv_); break; \
  case 2: ACC_CASE(2,Av,Bv_); break; case 3: ACC_CASE(3,Av,Bv_); break; \
  case 4: ACC_CASE(4,Av,Bv_); break; case 5: ACC_CASE(5,Av,Bv_); break; \
  case 6: ACC_CASE(6,Av,Bv_); break; default: ACC_CASE(7,Av,Bv_); break; }

__global__ __launch_bounds__(256, 4) void gmm_stats_fb(const float* __restrict__ mu,
                                                       const int* __restrict__ lab,
                                                       float* __restrict__ ws, int B) {
  const int tid = threadIdx.x;
  const int a_blk = tid >> 4, b_blk = tid & 15;
  const int rpb = (B + 1023) / 1024;
  const long rbase = (long)blockIdx.x * rpb;
  float facc[G][4]; float msum[G][2];
  #pragma unroll
  for (int g = 0; g < G; ++g) { facc[g][0]=facc[g][1]=facc[g][2]=facc[g][3]=0.f; msum[g][0]=msum[g][1]=0.f; }
  const float2* __restrict__ mu2 = reinterpret_cast<const float2*>(mu);
  for (long r = rbase; r < rbase + rpb && r < B; ++r) {
    const float2 Av = mu2[r * 16 + a_blk];
    const float2 Bv_ = mu2[r * 16 + b_blk];
    const int g0 = RF(lab[r]);
    PROC(g0, Av, Bv_);
  }
  const int arow = a_blk * 2, bcol = b_blk * 2;
  #pragma unroll
  for (int g = 0; g < G; ++g) {
    float* base = &ws[RAW_OFF + g * K * K];
    atomicAdd(base + (arow)*K + bcol, facc[g][0]);
    atomicAdd(base + (arow)*K + bcol + 1, facc[g][1]);
    atomicAdd(base + (arow+1)*K + bcol, facc[g][2]);
    atomicAdd(base + (arow+1)*K + bcol + 1, facc[g][3]);
  }
  if (a_blk == 0)
    #pragma unroll
    for (int g = 0; g < G; ++g) {
      atomicAdd(&ws[MUSUM_OFF + g*K + bcol], msum[g][0]);
      atomicAdd(&ws[MUSUM_OFF + g*K + bcol + 1], msum[g][1]);
    }
}

// ---------------- finalize (fp64, validated rounds 2/5-10) ----------------
__global__ __launch_bounds__(512, 1) void gmm_finalize(const float* __restrict__ ws,
                                                       float* __restrict__ out, int B) {
  __shared__ double sig[G][K][K];
  __shared__ double inv[G][K][K];
  __shared__ double mg[G][K];
  __shared__ double ldet[G];
  __shared__ double cshared[G];
  __shared__ double pairsum[G];
  const int tid = threadIdx.x;
  const int w = tid >> 6;
  const int lane = tid & 63;

  if (tid < G) cshared[tid] = (double)ws[CNT_OFF + tid];
  __syncthreads();
  const double cinv = 1.0 / cshared[w];
  if (lane < K) mg[w][lane] = (double)ws[MUSUM_OFF + w * K + lane] * cinv;
  __syncthreads();
  for (int e = lane; e < K * K; e += 64) {
    const int a = e >> 5, b = e & 31;
    double s = (double)ws[RAW_OFF + w * K * K + e] * cinv - mg[w][a] * mg[w][b];
    if (a == b) s += (double)SIGMA_V;
    sig[w][a][b] = s;
  }
  __syncthreads();

  const int c = lane & 31;
  double col[K];
  #pragma unroll
  for (int i2 = 0; i2 < K; ++i2) {
    double sv = sig[w][i2][c];
    col[i2] = (lane < K) ? sv : ((i2 == c) ? 1.0 : 0.0);
  }
  double ld = 0.0;
  #pragma unroll
  for (int j2 = 0; j2 < K; ++j2) {
    double rowj = col[j2];
    double p = __shfl(rowj, j2);
    double pinv = 1.0 / p;
    ld += log(p);
    double scaled = rowj * pinv;
    #pragma unroll
    for (int i2 = 0; i2 < K; ++i2) {
      if (i2 == j2) continue;
      double bij = __shfl(col[i2], j2);
      col[i2] = fma(-bij, scaled, col[i2]);
    }
    col[j2] = scaled;
  }
  if (lane >= K) {
    #pragma unroll
    for (int i2 = 0; i2 < K; ++i2) inv[w][i2][lane - K] = col[i2];
  }
  if (lane == 0) ldet[w] = ld;
  __syncthreads();

  double accp = 0.0;
  for (int jj = 0; jj < G; ++jj) {
    const bool ok = (w < G - 1) && (jj >= 1) && (w != jj);
    if (ok) {
      double t = 0.0;
      for (int e = lane; e < K * K; e += 64) {
        const int a = e >> 5, b = e & 31;
        const double da = mg[jj][a] - mg[w][a];
        const double db = mg[jj][b] - mg[w][b];
        t += inv[jj][a][b] * (sig[w][a][b] + da * db);
      }
      #pragma unroll
      for (int off = 32; off >= 1; off >>= 1) t += __shfl_xor(t, off);
      if (lane == 0) accp += 0.5 * (t - (double)K + ldet[jj] - ldet[w]) * cshared[w] * cshared[jj];
    }
  }
  if (lane == 0) pairsum[w] = accp;
  __syncthreads();
  if (tid == 0) {
    double tot = 0.0;
    #pragma unroll
    for (int q = 0; q < G; ++q) tot += pairsum[q];
    const double Bf = (double)B;
    out[0] = (float)(tot / (Bf * Bf));
  }
}

extern "C" void kernel_launch(void* const* d_in, const int* in_sizes, int n_in,
                              void* d_out, int out_size, void* d_ws, size_t ws_size,
                              hipStream_t stream) {
  const float* mu = (const float*)d_in[0];
  const int* lab = (const int*)d_in[1];
  float* ws = (float*)d_ws;
  float* out = (float*)d_out;
  const int B = in_sizes[1];

  hipMemsetAsync(d_ws, 0, (size_t)WS_FLOATS * 4, stream);

  if (B % (TILE * TBLK) == 0) {
    hipLaunchKernelGGL(gmm_stats4, dim3(B / (TILE * TBLK)), dim3(256), 0, stream, mu, lab, ws);
  } else {
    hipLaunchKernelGGL(gmm_histf, dim3(256), dim3(256), 0, stream, lab, ws, B);
    hipLaunchKernelGGL(gmm_stats_fb, dim3(1024), dim3(256), 0, stream, mu, lab, ws, B);
  }
  hipLaunchKernelGGL(gmm_finalize, dim3(1), dim3(512), 0, stream, ws, out, B);
}

// Round 12
// 238.561 us; speedup vs baseline: 1.3476x; 1.3476x over previous
//
#include <hip/hip_runtime.h>
#include <math.h>

#define K 32
#define G 8
#define SIGMA_V 1.0f
#define RF __builtin_amdgcn_readfirstlane
#define RPB 512            // rows per stats block (4 waves x 128)
#define RPW 128            // rows per wave

// ws layout (4-byte units)
#define RAW_OFF   0        // float[G*K*K] = 8192
#define MUSUM_OFF 8192     // float[G*K]   = 256
#define CNT_OFF   8448     // float[G]
#define ICNT_OFF  8456     // int[G]
#define CUR_OFF   8464     // int[G]
#define DONE_OFF  8472     // int[1]
#define DESC_OFF  8480     // int[3 * nblk]
#define IDX_OFF   16384    // int[B + 16*G]
#define HDR_INTS  16384

#define WAITV(n) asm volatile("s_waitcnt vmcnt(" #n ")" ::: "memory")
typedef __attribute__((address_space(3))) void lds_void;
typedef __attribute__((address_space(3))) float lds_float;
typedef __attribute__((address_space(1))) void glb_void;
#define GLL(gsrc, ldst) __builtin_amdgcn_global_load_lds((const glb_void*)(gsrc), (lds_void*)(ldst), 16, 0, 0)

typedef float f32x4 __attribute__((ext_vector_type(4)));
// inline-asm LDS read: invisible to the compiler's alias analysis, so it cannot
// insert conservative vmcnt(0) drains between GLL and consumption (the R9/R10 killer).
#define DSR(d, base, OFF) \
  asm volatile("ds_read_b128 %0, %1 offset:%2" : "=v"(d) : "v"(base), "i"(OFF))

// ---------------- histogram + fused prep (last block) — validated R10 ----------------
__global__ __launch_bounds__(256, 8) void gmm_hist(const int* __restrict__ lab,
                                                   float* __restrict__ ws,
                                                   int* __restrict__ wsI, int B, int nblk) {
  __shared__ int h[G];
  __shared__ int amLast;
  __shared__ int off[G], bb[G + 1], scnt[G];
  const int tid = threadIdx.x;
  if (tid < G) h[tid] = 0;
  __syncthreads();
  int c[G];
  #pragma unroll
  for (int g = 0; g < G; ++g) c[g] = 0;
  const int nt = gridDim.x * blockDim.x;
  const int4* lab4 = reinterpret_cast<const int4*>(lab);
  for (int i = blockIdx.x * blockDim.x + tid; i < B / 4; i += nt) {
    const int4 v = lab4[i];
    #pragma unroll
    for (int g = 0; g < G; ++g)
      c[g] += (v.x == g) + (v.y == g) + (v.z == g) + (v.w == g);
  }
  const int lane = tid & 63;
  #pragma unroll
  for (int g = 0; g < G; ++g) {
    int t = c[g];
    #pragma unroll
    for (int o = 32; o >= 1; o >>= 1) t += __shfl_xor(t, o);
    if (lane == 0) atomicAdd(&h[g], t);
  }
  __syncthreads();
  if (tid < G) atomicAdd(&wsI[ICNT_OFF + tid], h[tid]);
  __syncthreads();
  if (tid == 0) {
    __threadfence();
    amLast = (atomicAdd(&wsI[DONE_OFF], 1) == (int)gridDim.x - 1);
  }
  __syncthreads();
  if (!amLast) return;

  if (tid == 0) {
    int o = 0, b = 0;
    for (int g = 0; g < G; ++g) {
      const int cc = atomicAdd(&wsI[ICNT_OFF + g], 0);
      scnt[g] = cc; off[g] = o; bb[g] = b;
      ws[CNT_OFF + g] = (float)cc;
      wsI[CUR_OFF + g] = o;
      o = (o + cc + 15) & ~15;
      b += (cc + RPB - 1) / RPB;
    }
    bb[G] = b;
  }
  __syncthreads();
  for (int t = tid; t < nblk; t += blockDim.x) {
    int st = 0, cn = 0, gg = 0;
    #pragma unroll
    for (int g = 0; g < G; ++g) {
      if (t >= bb[g] && t < bb[g + 1]) {
        const int k = t - bb[g];
        st = off[g] + k * RPB;
        const int rem = scnt[g] - k * RPB;
        cn = rem < RPB ? rem : RPB;
        gg = g;
      }
    }
    wsI[DESC_OFF + 3 * t]     = st;
    wsI[DESC_OFF + 3 * t + 1] = cn;
    wsI[DESC_OFF + 3 * t + 2] = gg;
  }
}

// ---------------- scatter: LDS counting-sort, coalesced writes — validated R10 ----------------
__global__ __launch_bounds__(256, 8) void gmm_scatter(const int* __restrict__ lab,
                                                      int* __restrict__ wsI, int B) {
  __shared__ int lcnt[G], lofs[G + 1], lbase[G], lpos[G];
  __shared__ int sorted[1024];
  const int tid = threadIdx.x;
  const int base = blockIdx.x * 1024;
  if (tid < G) { lcnt[tid] = 0; lpos[tid] = 0; }
  __syncthreads();
  const int4 v = *reinterpret_cast<const int4*>(lab + base + tid * 4);
  atomicAdd(&lcnt[v.x], 1); atomicAdd(&lcnt[v.y], 1);
  atomicAdd(&lcnt[v.z], 1); atomicAdd(&lcnt[v.w], 1);
  __syncthreads();
  if (tid == 0) {
    int o = 0;
    #pragma unroll
    for (int g = 0; g < G; ++g) { lofs[g] = o; o += lcnt[g]; }
    lofs[G] = o;
  }
  __syncthreads();
  if (tid < G) lbase[tid] = atomicAdd(&wsI[CUR_OFF + tid], lcnt[tid]);
  int p;
  p = atomicAdd(&lpos[v.x], 1); sorted[lofs[v.x] + p] = base + tid * 4;
  p = atomicAdd(&lpos[v.y], 1); sorted[lofs[v.y] + p] = base + tid * 4 + 1;
  p = atomicAdd(&lpos[v.z], 1); sorted[lofs[v.z] + p] = base + tid * 4 + 2;
  p = atomicAdd(&lpos[v.w], 1); sorted[lofs[v.w] + p] = base + tid * 4 + 3;
  __syncthreads();
  for (int e = tid; e < 1024; e += 256) {
    const int val = sorted[e];
    int gg = 0;
    #pragma unroll
    for (int g = 1; g < G; ++g) gg += (e >= lofs[g]);
    wsI[IDX_OFF + lbase[gg] + (e - lofs[gg])] = val;
  }
}

// ---------------- stats: job-deep MLP — burst 16 GLLs, counted-vmcnt consume ----------------
#define OUTER(a, b) { \
  acc[0]=fmaf(a.x,b.x,acc[0]);   acc[1]=fmaf(a.x,b.y,acc[1]);   acc[2]=fmaf(a.x,b.z,acc[2]);   acc[3]=fmaf(a.x,b.w,acc[3]); \
  acc[4]=fmaf(a.y,b.x,acc[4]);   acc[5]=fmaf(a.y,b.y,acc[5]);   acc[6]=fmaf(a.y,b.z,acc[6]);   acc[7]=fmaf(a.y,b.w,acc[7]); \
  acc[8]=fmaf(a.z,b.x,acc[8]);   acc[9]=fmaf(a.z,b.y,acc[9]);   acc[10]=fmaf(a.z,b.z,acc[10]); acc[11]=fmaf(a.z,b.w,acc[11]); \
  acc[12]=fmaf(a.w,b.x,acc[12]); acc[13]=fmaf(a.w,b.y,acc[13]); acc[14]=fmaf(a.w,b.z,acc[14]); acc[15]=fmaf(a.w,b.w,acc[15]); \
  ms[0]+=b.x; ms[1]+=b.y; ms[2]+=b.z; ms[3]+=b.w; }

// 4 rows at byte offset OFF within the wave's stage (abase/bbase carry i8/j8 lane offsets)
#define ROWS4(OFF) do { \
  f32x4 a0,b0,a1,b1,a2,b2,a3,b3; \
  DSR(a0, abase, OFF);       DSR(b0, bbase, OFF); \
  DSR(a1, abase, (OFF)+128); DSR(b1, bbase, (OFF)+128); \
  DSR(a2, abase, (OFF)+256); DSR(b2, bbase, (OFF)+256); \
  DSR(a3, abase, (OFF)+384); DSR(b3, bbase, (OFF)+384); \
  asm volatile("s_waitcnt lgkmcnt(0)" ::: "memory"); \
  __builtin_amdgcn_sched_barrier(0); \
  OUTER(a0, b0); OUTER(a1, b1); OUTER(a2, b2); OUTER(a3, b3); \
} while (0)

// consume 2 chunks (16 rows) after a counted wait: WN = 16 - chunks_consumed_after
#define CPAIR(WN, OFF) do { \
  WAITV(WN); \
  ROWS4(OFF); ROWS4((OFF)+512); ROWS4((OFF)+1024); ROWS4((OFF)+1536); \
} while (0)

__global__ __launch_bounds__(256, 2) void gmm_stats5(const float* __restrict__ mu,
                                                     const int* __restrict__ wsI,
                                                     float* __restrict__ ws) {
  __shared__ float stg[16384];               // [4 waves][16 chunks][8 rows][32 floats] = 64 KB
  __shared__ int idxl[512];                  // [4 waves][128]
  const int bd  = blockIdx.x * 3;
  const int s   = RF(wsI[DESC_OFF + bd]);
  const int cnt = RF(wsI[DESC_OFF + bd + 1]);
  const int g   = RF(wsI[DESC_OFF + bd + 2]);
  if (cnt <= 0) return;                      // uniform for whole block

  const int tid = threadIdx.x, wave = tid >> 6, lane = tid & 63;
  const int i8 = lane >> 3, j8 = lane & 7;   // compute: 8x8 lane grid, 4x4 tile
  const int lg8 = lane >> 3, lf = lane & 7;  // staging mapping
  float acc[16], ms[4];
  #pragma unroll
  for (int e = 0; e < 16; ++e) acc[e] = 0.f;
  ms[0] = ms[1] = ms[2] = ms[3] = 0.f;

  int wcnt = cnt - wave * RPW;
  wcnt = wcnt < 0 ? 0 : (wcnt > RPW ? RPW : wcnt);
  const int* idxp = wsI + IDX_OFF + s + wave * RPW;
  float* wstg = &stg[wave * 4096];
  const unsigned wbase = (unsigned)(size_t)(lds_float*)wstg;   // LDS byte addr of wave stage
  const unsigned abase = wbase + i8 * 16;
  const unsigned bbase = wbase + j8 * 16;

  if (wcnt == RPW) {
    // idx: 2 vector loads -> drain once (only these pollute vmcnt) -> LDS -> per-chunk bcast
    const int ia = idxp[lane];
    const int ib = idxp[64 + lane];
    WAITV(0);
    idxl[wave * 128 + lane] = ia;
    idxl[wave * 128 + 64 + lane] = ib;
    // burst all 16 chunk GLLs back-to-back: 15 stay in flight during first compute
    #pragma unroll
    for (int c = 0; c < 16; ++c) {
      const int m = idxl[wave * 128 + c * 8 + lg8];   // broadcast read (compiler lgkm-synced)
      GLL(mu + (size_t)(unsigned)m * K + lf * 4, wstg + c * 256);
    }
    CPAIR(14, 0);      CPAIR(12, 2048);  CPAIR(10, 4096);  CPAIR(8, 6144);
    CPAIR(6, 8192);    CPAIR(4, 10240);  CPAIR(2, 12288);  CPAIR(0, 14336);
  } else {
    const int nch = wcnt >> 3;
    for (int k = 0; k < nch; ++k) {          // rare boundary waves: simple drains
      const int iv = idxp[k * 8 + lg8];
      WAITV(0);
      GLL(mu + (size_t)(unsigned)iv * K + lf * 4, wstg);
      WAITV(0);
      f32x4 a0, b0;
      #pragma unroll
      for (int r = 0; r < 8; ++r) {
        DSR(a0, abase, 0); DSR(b0, bbase, 0);   // offset added via abase2 below
        // (use runtime-adjusted bases per row)
        (void)a0; (void)b0;
        break;
      }
      // straightforward per-row consume with explicit drains (correctness-first path)
      for (int r = 0; r < 8; ++r) {
        const float4 a = *reinterpret_cast<const float4*>(&wstg[r * 32 + i8 * 4]);
        const float4 bv = *reinterpret_cast<const float4*>(&wstg[r * 32 + j8 * 4]);
        OUTER(a, bv);
      }
    }
    for (int q = nch << 3; q < wcnt; ++q) {  // tail <= 7 rows: direct loads
      const int r = idxp[q];
      const float* rp = mu + (size_t)(unsigned)r * K;
      const float4 a  = *reinterpret_cast<const float4*>(rp + i8 * 4);
      const float4 bv = *reinterpret_cast<const float4*>(rp + j8 * 4);
      OUTER(a, bv);
    }
  }

  // flush: overlay reuses stage LDS after barrier; element-major (conflict-free)
  __syncthreads();
  #pragma unroll
  for (int e = 0; e < 16; ++e) stg[wave * 1056 + e * 64 + lane] = acc[e];
  if (i8 == 0) {
    #pragma unroll
    for (int e = 0; e < 4; ++e) stg[wave * 1056 + 1024 + j8 * 4 + e] = ms[e];
  }
  __syncthreads();
  for (int t = tid; t < 1056; t += 256) {
    const float sm = stg[t] + stg[1056 + t] + stg[2112 + t] + stg[3168 + t];
    if (t < 1024) {
      const int e = t >> 6, ln = t & 63;
      const int row = 4 * (ln >> 3) + (e >> 2), col = 4 * (ln & 7) + (e & 3);
      atomicAdd(ws + RAW_OFF + g * K * K + row * K + col, sm);
    } else {
      atomicAdd(ws + MUSUM_OFF + g * K + (t - 1024), sm);
    }
  }
}

// ---------------- fallback stats (ws too small): round-2 style ----------------
#define ACC_CASE(gc_, Av, Bv_) do{ \
  facc[gc_][0]=fmaf(Av.x,Bv_.x,facc[gc_][0]); facc[gc_][1]=fmaf(Av.x,Bv_.y,facc[gc_][1]); \
  facc[gc_][2]=fmaf(Av.y,Bv_.x,facc[gc_][2]); facc[gc_][3]=fmaf(Av.y,Bv_.y,facc[gc_][3]); \
  if (a_blk==0){ msum[gc_][0]+=Bv_.x; msum[gc_][1]+=Bv_.y; } }while(0)
#define PROC(gv, Av, Bv_) switch(gv){ \
  case 0: ACC_CASE(0,Av,Bv_); break; case 1: ACC_CASE(1,Av,Bv_); break; \
  case 2: ACC_CASE(2,Av,Bv_); break; case 3: ACC_CASE(3,Av,Bv_); break; \
  case 4: ACC_CASE(4,Av,Bv_); break; case 5: ACC_CASE(5,Av,Bv_); break; \
  case 6: ACC_CASE(6,Av,Bv_); break; default: ACC_CASE(7,Av,Bv_); break; }

__global__ __launch_bounds__(256, 4) void gmm_stats_fb(const float* __restrict__ mu,
                                                       const int* __restrict__ lab,
                                                       float* __restrict__ ws, int B) {
  const int tid = threadIdx.x;
  const int a_blk = tid >> 4, b_blk = tid & 15;
  const int rpb = (B + 1023) / 1024;
  const long rbase = (long)blockIdx.x * rpb;
  float facc[G][4]; float msum[G][2];
  #pragma unroll
  for (int g = 0; g < G; ++g) { facc[g][0]=facc[g][1]=facc[g][2]=facc[g][3]=0.f; msum[g][0]=msum[g][1]=0.f; }
  const float2* __restrict__ mu2 = reinterpret_cast<const float2*>(mu);
  for (long r = rbase; r < rbase + rpb && r < B; ++r) {
    const float2 Av = mu2[r * 16 + a_blk];
    const float2 Bv_ = mu2[r * 16 + b_blk];
    const int g0 = RF(lab[r]);
    PROC(g0, Av, Bv_);
  }
  const int arow = a_blk * 2, bcol = b_blk * 2;
  #pragma unroll
  for (int g = 0; g < G; ++g) {
    float* base = &ws[RAW_OFF + g * K * K];
    atomicAdd(base + (arow)*K + bcol, facc[g][0]);
    atomicAdd(base + (arow)*K + bcol + 1, facc[g][1]);
    atomicAdd(base + (arow+1)*K + bcol, facc[g][2]);
    atomicAdd(base + (arow+1)*K + bcol + 1, facc[g][3]);
  }
  if (a_blk == 0)
    #pragma unroll
    for (int g = 0; g < G; ++g) {
      atomicAdd(&ws[MUSUM_OFF + g*K + bcol], msum[g][0]);
      atomicAdd(&ws[MUSUM_OFF + g*K + bcol + 1], msum[g][1]);
    }
}

// ---------------- finalize (fp64, validated rounds 2/5-11) ----------------
__global__ __launch_bounds__(512, 1) void gmm_finalize(const float* __restrict__ ws,
                                                       float* __restrict__ out, int B) {
  __shared__ double sig[G][K][K];
  __shared__ double inv[G][K][K];
  __shared__ double mg[G][K];
  __shared__ double ldet[G];
  __shared__ double cshared[G];
  __shared__ double pairsum[G];
  const int tid = threadIdx.x;
  const int w = tid >> 6;
  const int lane = tid & 63;

  if (tid < G) cshared[tid] = (double)ws[CNT_OFF + tid];
  __syncthreads();
  const double cinv = 1.0 / cshared[w];
  if (lane < K) mg[w][lane] = (double)ws[MUSUM_OFF + w * K + lane] * cinv;
  __syncthreads();
  for (int e = lane; e < K * K; e += 64) {
    const int a = e >> 5, b = e & 31;
    double s = (double)ws[RAW_OFF + w * K * K + e] * cinv - mg[w][a] * mg[w][b];
    if (a == b) s += (double)SIGMA_V;
    sig[w][a][b] = s;
  }
  __syncthreads();

  const int c = lane & 31;
  double col[K];
  #pragma unroll
  for (int i2 = 0; i2 < K; ++i2) {
    double sv = sig[w][i2][c];
    col[i2] = (lane < K) ? sv : ((i2 == c) ? 1.0 : 0.0);
  }
  double ld = 0.0;
  #pragma unroll
  for (int j2 = 0; j2 < K; ++j2) {
    double rowj = col[j2];
    double p = __shfl(rowj, j2);
    double pinv = 1.0 / p;
    ld += log(p);
    double scaled = rowj * pinv;
    #pragma unroll
    for (int i2 = 0; i2 < K; ++i2) {
      if (i2 == j2) continue;
      double bij = __shfl(col[i2], j2);
      col[i2] = fma(-bij, scaled, col[i2]);
    }
    col[j2] = scaled;
  }
  if (lane >= K) {
    #pragma unroll
    for (int i2 = 0; i2 < K; ++i2) inv[w][i2][lane - K] = col[i2];
  }
  if (lane == 0) ldet[w] = ld;
  __syncthreads();

  double accp = 0.0;
  for (int jj = 0; jj < G; ++jj) {
    const bool ok = (w < G - 1) && (jj >= 1) && (w != jj);
    if (ok) {
      double t = 0.0;
      for (int e = lane; e < K * K; e += 64) {
        const int a = e >> 5, b = e & 31;
        const double da = mg[jj][a] - mg[w][a];
        const double db = mg[jj][b] - mg[w][b];
        t += inv[jj][a][b] * (sig[w][a][b] + da * db);
      }
      #pragma unroll
      for (int off = 32; off >= 1; off >>= 1) t += __shfl_xor(t, off);
      if (lane == 0) accp += 0.5 * (t - (double)K + ldet[jj] - ldet[w]) * cshared[w] * cshared[jj];
    }
  }
  if (lane == 0) pairsum[w] = accp;
  __syncthreads();
  if (tid == 0) {
    double tot = 0.0;
    #pragma unroll
    for (int q = 0; q < G; ++q) tot += pairsum[q];
    const double Bf = (double)B;
    out[0] = (float)(tot / (Bf * Bf));
  }
}

extern "C" void kernel_launch(void* const* d_in, const int* in_sizes, int n_in,
                              void* d_out, int out_size, void* d_ws, size_t ws_size,
                              hipStream_t stream) {
  const float* mu = (const float*)d_in[0];
  const int* lab = (const int*)d_in[1];
  float* ws = (float*)d_ws;
  int* wsI = (int*)d_ws;
  float* out = (float*)d_out;
  const int B = in_sizes[1];

  hipMemsetAsync(d_ws, 0, (size_t)DESC_OFF * 4, stream);   // zeroes ICNT/CUR/DONE each call

  const size_t need = (size_t)(HDR_INTS + B + 16 * G + 32) * 4;
  if (ws_size >= need && (B & 1023) == 0) {
    const int nblk = (B + RPB - 1) / RPB + G;
    hipLaunchKernelGGL(gmm_hist, dim3(256), dim3(256), 0, stream, lab, ws, wsI, B, nblk);
    hipLaunchKernelGGL(gmm_scatter, dim3(B / 1024), dim3(256), 0, stream, lab, wsI, B);
    hipLaunchKernelGGL(gmm_stats5, dim3(nblk), dim3(256), 0, stream, mu, wsI, ws);
  } else {
    hipLaunchKernelGGL(gmm_hist, dim3(256), dim3(256), 0, stream, lab, ws, wsI, B, 0);
    hipLaunchKernelGGL(gmm_stats_fb, dim3(1024), dim3(256), 0, stream, mu, lab, ws, B);
  }
  hipLaunchKernelGGL(gmm_finalize, dim3(1), dim3(512), 0, stream, ws, out, B);
}

// Round 13
// 215.251 us; speedup vs baseline: 1.4936x; 1.1083x over previous
//
#include <hip/hip_runtime.h>
#include <math.h>

#define K 32
#define G 8
#define SIGMA_V 1.0f
#define RF __builtin_amdgcn_readfirstlane
#define RPB 512            // rows per stats block (4 waves x 128)
#define RPW 128            // rows per wave

// ws layout (4-byte units)
#define RAW_OFF   0        // float[G*K*K] = 8192
#define MUSUM_OFF 8192     // float[G*K]   = 256
#define CNT_OFF   8448     // float[G]
#define ICNT_OFF  8456     // int[G]
#define CUR_OFF   8464     // int[G]
#define DESC_OFF  8480     // int[3 * nblk] (nblk = 2056 -> 6168 ints < 7904)
#define IDX_OFF   16384    // int[B + 16*G]
#define HDR_INTS  16384

#define WAITV(n) asm volatile("s_waitcnt vmcnt(" #n ")" ::: "memory")
typedef __attribute__((address_space(3))) void lds_void;
typedef __attribute__((address_space(1))) void glb_void;
#define GLL(gsrc, ldst) __builtin_amdgcn_global_load_lds((const glb_void*)(gsrc), (lds_void*)(ldst), 16, 0, 0)

// ---------------- histogram (plain, R6-proven) ----------------
__global__ __launch_bounds__(256, 8) void gmm_hist(const int* __restrict__ lab,
                                                   int* __restrict__ wsI, int B) {
  __shared__ int h[G];
  if (threadIdx.x < G) h[threadIdx.x] = 0;
  __syncthreads();
  int c[G];
  #pragma unroll
  for (int g = 0; g < G; ++g) c[g] = 0;
  const int nt = gridDim.x * blockDim.x;
  const int4* lab4 = reinterpret_cast<const int4*>(lab);
  for (int i = blockIdx.x * blockDim.x + threadIdx.x; i < B / 4; i += nt) {
    const int4 v = lab4[i];
    #pragma unroll
    for (int g = 0; g < G; ++g)
      c[g] += (v.x == g) + (v.y == g) + (v.z == g) + (v.w == g);
  }
  const int lane = threadIdx.x & 63;
  #pragma unroll
  for (int g = 0; g < G; ++g) {
    int t = c[g];
    #pragma unroll
    for (int off = 32; off >= 1; off >>= 1) t += __shfl_xor(t, off);
    if (lane == 0) atomicAdd(&h[g], t);
  }
  __syncthreads();
  if (threadIdx.x < G) atomicAdd(&wsI[ICNT_OFF + threadIdx.x], h[threadIdx.x]);
}

// ---------------- prep: standalone 1-block (R7-proven), 16-padded offsets ----------------
__global__ void gmm_prep(float* __restrict__ ws, int* __restrict__ wsI, int B, int nblk) {
  __shared__ int off[G], bb[G + 1], scnt[G];
  const int tid = threadIdx.x;
  if (tid == 0) {
    int o = 0, b = 0;
    for (int g = 0; g < G; ++g) {
      const int c = wsI[ICNT_OFF + g];
      scnt[g] = c; off[g] = o; bb[g] = b;
      ws[CNT_OFF + g] = (float)c;
      wsI[CUR_OFF + g] = o;
      o = (o + c + 15) & ~15;          // 16-int padding: block starts stay 16-aligned
      b += (c + RPB - 1) / RPB;
    }
    bb[G] = b;
  }
  __syncthreads();
  for (int t = tid; t < nblk; t += blockDim.x) {
    int st = 0, cn = 0, gg = 0;
    #pragma unroll
    for (int g = 0; g < G; ++g) {
      if (t >= bb[g] && t < bb[g + 1]) {
        const int k = t - bb[g];
        st = off[g] + k * RPB;
        const int rem = scnt[g] - k * RPB;
        cn = rem < RPB ? rem : RPB;
        gg = g;
      }
    }
    wsI[DESC_OFF + 3 * t]     = st;
    wsI[DESC_OFF + 3 * t + 1] = cn;
    wsI[DESC_OFF + 3 * t + 2] = gg;
  }
}

// ---------------- scatter (R6-proven direct version) ----------------
__global__ __launch_bounds__(256, 8) void gmm_scatter(const int* __restrict__ lab,
                                                      int* __restrict__ wsI, int B) {
  __shared__ int lcnt[G], lbase[G], lpos[G];
  const int tid = threadIdx.x;
  const int base = blockIdx.x * 1024;
  if (tid < G) { lcnt[tid] = 0; lpos[tid] = 0; }
  __syncthreads();
  const int4 v = *reinterpret_cast<const int4*>(lab + base + tid * 4);
  atomicAdd(&lcnt[v.x], 1); atomicAdd(&lcnt[v.y], 1);
  atomicAdd(&lcnt[v.z], 1); atomicAdd(&lcnt[v.w], 1);
  __syncthreads();
  if (tid < G) lbase[tid] = atomicAdd(&wsI[CUR_OFF + tid], lcnt[tid]);
  __syncthreads();
  int p;
  p = atomicAdd(&lpos[v.x], 1); wsI[IDX_OFF + lbase[v.x] + p] = base + tid * 4;
  p = atomicAdd(&lpos[v.y], 1); wsI[IDX_OFF + lbase[v.y] + p] = base + tid * 4 + 1;
  p = atomicAdd(&lpos[v.z], 1); wsI[IDX_OFF + lbase[v.z] + p] = base + tid * 4 + 2;
  p = atomicAdd(&lpos[v.w], 1); wsI[IDX_OFF + lbase[v.w] + p] = base + tid * 4 + 3;
}

// ---------------- stats: R10-proven 4-deep LDS pipeline, 8-row chunks ----------------
#define OUTER(a, b) { \
  acc[0]=fmaf(a.x,b.x,acc[0]);   acc[1]=fmaf(a.x,b.y,acc[1]);   acc[2]=fmaf(a.x,b.z,acc[2]);   acc[3]=fmaf(a.x,b.w,acc[3]); \
  acc[4]=fmaf(a.y,b.x,acc[4]);   acc[5]=fmaf(a.y,b.y,acc[5]);   acc[6]=fmaf(a.y,b.z,acc[6]);   acc[7]=fmaf(a.y,b.w,acc[7]); \
  acc[8]=fmaf(a.z,b.x,acc[8]);   acc[9]=fmaf(a.z,b.y,acc[9]);   acc[10]=fmaf(a.z,b.z,acc[10]); acc[11]=fmaf(a.z,b.w,acc[11]); \
  acc[12]=fmaf(a.w,b.x,acc[12]); acc[13]=fmaf(a.w,b.y,acc[13]); acc[14]=fmaf(a.w,b.z,acc[14]); acc[15]=fmaf(a.w,b.w,acc[15]); \
  ms[0]+=b.x; ms[1]+=b.y; ms[2]+=b.z; ms[3]+=b.w; }

#define STAGE8(iv, bi) do { \
  float* db = &lds[wave * 1024 + (bi) * 256]; \
  GLL(mu + (size_t)(unsigned)(iv) * K + lf * 4, db); \
} while (0)

#define COMPUTE8(bi) do { \
  const float* sb = &lds[wave * 1024 + (bi) * 256]; \
  _Pragma("unroll") \
  for (int r = 0; r < 8; ++r) { \
    const float4 a  = *reinterpret_cast<const float4*>(&sb[r * 32 + i8 * 4]); \
    const float4 bv = *reinterpret_cast<const float4*>(&sb[r * 32 + j8 * 4]); \
    OUTER(a, bv); \
  } \
} while (0)

__global__ __launch_bounds__(256, 4) void gmm_stats3(const float* __restrict__ mu,
                                                     const int* __restrict__ wsI,
                                                     float* __restrict__ ws) {
  __shared__ float lds[4224];                // stage [4 waves][4 bufs][8][32] + flush overlay
  const int bd  = blockIdx.x * 3;
  const int s   = RF(wsI[DESC_OFF + bd]);
  const int cnt = RF(wsI[DESC_OFF + bd + 1]);
  const int g   = RF(wsI[DESC_OFF + bd + 2]);
  if (cnt <= 0) return;                      // uniform for whole block

  const int tid = threadIdx.x, wave = tid >> 6, lane = tid & 63;
  const int i8 = lane >> 3, j8 = lane & 7;   // compute mapping (4x4 tile per lane)
  const int lg8 = lane >> 3, lf = lane & 7;  // staging mapping
  float acc[16], ms[4];
  #pragma unroll
  for (int e = 0; e < 16; ++e) acc[e] = 0.f;
  ms[0] = ms[1] = ms[2] = ms[3] = 0.f;

  int wcnt = cnt - wave * RPW;
  wcnt = wcnt < 0 ? 0 : (wcnt > RPW ? RPW : wcnt);
  const int* idxp = wsI + IDX_OFF + s + wave * RPW;
  const int nch = wcnt >> 3;                 // 8-row chunks (16 for interior blocks)

  if (nch == 16) {
    const int i0 = idxp[lg8];                // I(0)
    int inext    = idxp[8 + lg8];            // I(1)
    WAITV(1); STAGE8(i0, 0);                 // G(0)
    {
      const int i1 = inext;
      inext = idxp[16 + lg8];                // I(2)
      WAITV(2); STAGE8(i1, 1);               // G(1)
    }
    {
      const int i2 = inext;
      inext = idxp[24 + lg8];                // I(3)
      WAITV(2); STAGE8(i2, 2);               // G(2)
    }
    #pragma unroll 1
    for (int k = 0; k < 12; ++k) {
      const int istage = inext;              // I(k+3)
      inext = idxp[(k + 4) * 8 + lg8];       // issue I(k+4)
      WAITV(2);
      STAGE8(istage, (k + 3) & 3);
      COMPUTE8(k & 3);
    }
    WAITV(1); STAGE8(inext, 15 & 3);
    COMPUTE8(12 & 3);
    COMPUTE8(13 & 3);
    WAITV(1); COMPUTE8(14 & 3);
    WAITV(0); COMPUTE8(15 & 3);
  } else {
    for (int k = 0; k < nch; ++k) {          // rare boundary blocks: simple drains
      const int iv = idxp[k * 8 + lg8];
      WAITV(0); STAGE8(iv, k & 3);
      WAITV(0); COMPUTE8(k & 3);
    }
  }
  for (int q = nch << 3; q < wcnt; ++q) {    // tail <= 7 rows: direct loads
    const int r = idxp[q];
    const float* rp = mu + (size_t)(unsigned)r * K;
    const float4 a  = *reinterpret_cast<const float4*>(rp + i8 * 4);
    const float4 bv = *reinterpret_cast<const float4*>(rp + j8 * 4);
    OUTER(a, bv);
  }

  // flush: overlay reuses stage LDS after barrier; element-major (conflict-free)
  __syncthreads();
  #pragma unroll
  for (int e = 0; e < 16; ++e) lds[wave * 1056 + e * 64 + lane] = acc[e];
  if (i8 == 0) {
    #pragma unroll
    for (int e = 0; e < 4; ++e) lds[wave * 1056 + 1024 + j8 * 4 + e] = ms[e];
  }
  __syncthreads();
  for (int t = tid; t < 1056; t += 256) {
    const float sm = lds[t] + lds[1056 + t] + lds[2112 + t] + lds[3168 + t];
    if (t < 1024) {
      const int e = t >> 6, ln = t & 63;
      const int row = 4 * (ln >> 3) + (e >> 2), col = 4 * (ln & 7) + (e & 3);
      atomicAdd(ws + RAW_OFF + g * K * K + row * K + col, sm);
    } else {
      atomicAdd(ws + MUSUM_OFF + g * K + (t - 1024), sm);
    }
  }
}

// ---------------- fallback stats (ws too small): round-2 style ----------------
#define ACC_CASE(gc_, Av, Bv_) do{ \
  facc[gc_][0]=fmaf(Av.x,Bv_.x,facc[gc_][0]); facc[gc_][1]=fmaf(Av.x,Bv_.y,facc[gc_][1]); \
  facc[gc_][2]=fmaf(Av.y,Bv_.x,facc[gc_][2]); facc[gc_][3]=fmaf(Av.y,Bv_.y,facc[gc_][3]); \
  if (a_blk==0){ msum[gc_][0]+=Bv_.x; msum[gc_][1]+=Bv_.y; } }while(0)
#define PROC(gv, Av, Bv_) switch(gv){ \
  case 0: ACC_CASE(0,Av,Bv_); break; case 1: ACC_CASE(1,Av,Bv_); break; \
  case 2: ACC_CASE(2,Av,Bv_); break; case 3: ACC_CASE(3,Av,Bv_); break; \
  case 4: ACC_CASE(4,Av,Bv_); break; case 5: ACC_CASE(5,Av,Bv_); break; \
  case 6: ACC_CASE(6,Av,Bv_); break; default: ACC_CASE(7,Av,Bv_); break; }

__global__ __launch_bounds__(256, 4) void gmm_stats_fb(const float* __restrict__ mu,
                                                       const int* __restrict__ lab,
                                                       float* __restrict__ ws, int B) {
  const int tid = threadIdx.x;
  const int a_blk = tid >> 4, b_blk = tid & 15;
  const int rpb = (B + 1023) / 1024;
  const long rbase = (long)blockIdx.x * rpb;
  float facc[G][4]; float msum[G][2];
  #pragma unroll
  for (int g = 0; g < G; ++g) { facc[g][0]=facc[g][1]=facc[g][2]=facc[g][3]=0.f; msum[g][0]=msum[g][1]=0.f; }
  const float2* __restrict__ mu2 = reinterpret_cast<const float2*>(mu);
  for (long r = rbase; r < rbase + rpb && r < B; ++r) {
    const float2 Av = mu2[r * 16 + a_blk];
    const float2 Bv_ = mu2[r * 16 + b_blk];
    const int g0 = RF(lab[r]);
    PROC(g0, Av, Bv_);
  }
  const int arow = a_blk * 2, bcol = b_blk * 2;
  #pragma unroll
  for (int g = 0; g < G; ++g) {
    float* base = &ws[RAW_OFF + g * K * K];
    atomicAdd(base + (arow)*K + bcol, facc[g][0]);
    atomicAdd(base + (arow)*K + bcol + 1, facc[g][1]);
    atomicAdd(base + (arow+1)*K + bcol, facc[g][2]);
    atomicAdd(base + (arow+1)*K + bcol + 1, facc[g][3]);
  }
  if (a_blk == 0)
    #pragma unroll
    for (int g = 0; g < G; ++g) {
      atomicAdd(&ws[MUSUM_OFF + g*K + bcol], msum[g][0]);
      atomicAdd(&ws[MUSUM_OFF + g*K + bcol + 1], msum[g][1]);
    }
}

// ---------------- finalize (fp64, validated rounds 2/5-12) ----------------
__global__ __launch_bounds__(512, 1) void gmm_finalize(const float* __restrict__ ws,
                                                       float* __restrict__ out, int B) {
  __shared__ double sig[G][K][K];
  __shared__ double inv[G][K][K];
  __shared__ double mg[G][K];
  __shared__ double ldet[G];
  __shared__ double cshared[G];
  __shared__ double pairsum[G];
  const int tid = threadIdx.x;
  const int w = tid >> 6;
  const int lane = tid & 63;

  if (tid < G) cshared[tid] = (double)ws[CNT_OFF + tid];
  __syncthreads();
  const double cinv = 1.0 / cshared[w];
  if (lane < K) mg[w][lane] = (double)ws[MUSUM_OFF + w * K + lane] * cinv;
  __syncthreads();
  for (int e = lane; e < K * K; e += 64) {
    const int a = e >> 5, b = e & 31;
    double s = (double)ws[RAW_OFF + w * K * K + e] * cinv - mg[w][a] * mg[w][b];
    if (a == b) s += (double)SIGMA_V;
    sig[w][a][b] = s;
  }
  __syncthreads();

  const int c = lane & 31;
  double col[K];
  #pragma unroll
  for (int i2 = 0; i2 < K; ++i2) {
    double sv = sig[w][i2][c];
    col[i2] = (lane < K) ? sv : ((i2 == c) ? 1.0 : 0.0);
  }
  double ld = 0.0;
  #pragma unroll
  for (int j2 = 0; j2 < K; ++j2) {
    double rowj = col[j2];
    double p = __shfl(rowj, j2);
    double pinv = 1.0 / p;
    ld += log(p);
    double scaled = rowj * pinv;
    #pragma unroll
    for (int i2 = 0; i2 < K; ++i2) {
      if (i2 == j2) continue;
      double bij = __shfl(col[i2], j2);
      col[i2] = fma(-bij, scaled, col[i2]);
    }
    col[j2] = scaled;
  }
  if (lane >= K) {
    #pragma unroll
    for (int i2 = 0; i2 < K; ++i2) inv[w][i2][lane - K] = col[i2];
  }
  if (lane == 0) ldet[w] = ld;
  __syncthreads();

  double accp = 0.0;
  for (int jj = 0; jj < G; ++jj) {
    const bool ok = (w < G - 1) && (jj >= 1) && (w != jj);
    if (ok) {
      double t = 0.0;
      for (int e = lane; e < K * K; e += 64) {
        const int a = e >> 5, b = e & 31;
        const double da = mg[jj][a] - mg[w][a];
        const double db = mg[jj][b] - mg[w][b];
        t += inv[jj][a][b] * (sig[w][a][b] + da * db);
      }
      #pragma unroll
      for (int off = 32; off >= 1; off >>= 1) t += __shfl_xor(t, off);
      if (lane == 0) accp += 0.5 * (t - (double)K + ldet[jj] - ldet[w]) * cshared[w] * cshared[jj];
    }
  }
  if (lane == 0) pairsum[w] = accp;
  __syncthreads();
  if (tid == 0) {
    double tot = 0.0;
    #pragma unroll
    for (int q = 0; q < G; ++q) tot += pairsum[q];
    const double Bf = (double)B;
    out[0] = (float)(tot / (Bf * Bf));
  }
}

extern "C" void kernel_launch(void* const* d_in, const int* in_sizes, int n_in,
                              void* d_out, int out_size, void* d_ws, size_t ws_size,
                              hipStream_t stream) {
  const float* mu = (const float*)d_in[0];
  const int* lab = (const int*)d_in[1];
  float* ws = (float*)d_ws;
  int* wsI = (int*)d_ws;
  float* out = (float*)d_out;
  const int B = in_sizes[1];

  hipMemsetAsync(d_ws, 0, (size_t)DESC_OFF * 4, stream);   // zeroes ICNT/CUR each call

  const size_t need = (size_t)(HDR_INTS + B + 16 * G + 32) * 4;
  if (ws_size >= need && (B & 1023) == 0) {
    const int nblk = (B + RPB - 1) / RPB + G;
    hipLaunchKernelGGL(gmm_hist, dim3(256), dim3(256), 0, stream, lab, wsI, B);
    hipLaunchKernelGGL(gmm_prep, dim3(1), dim3(256), 0, stream, ws, wsI, B, nblk);
    hipLaunchKernelGGL(gmm_scatter, dim3(B / 1024), dim3(256), 0, stream, lab, wsI, B);
    hipLaunchKernelGGL(gmm_stats3, dim3(nblk), dim3(256), 0, stream, mu, wsI, ws);
  } else {
    hipLaunchKernelGGL(gmm_hist, dim3(256), dim3(256), 0, stream, lab, wsI, B);
    hipLaunchKernelGGL(gmm_prep, dim3(1), dim3(256), 0, stream, ws, wsI, B, 0);
    hipLaunchKernelGGL(gmm_stats_fb, dim3(1024), dim3(256), 0, stream, mu, lab, ws, B);
  }
  hipLaunchKernelGGL(gmm_finalize, dim3(1), dim3(512), 0, stream, ws, out, B);
}